// Round 12
// baseline (5608.245 us; speedup 1.0000x reference)
//
#include <hip/hip_runtime.h>
#include <stdint.h>

typedef unsigned short u16;
typedef __attribute__((ext_vector_type(8))) short bf16x8;
typedef __attribute__((ext_vector_type(4))) float f32x4;

#define EE 512
#define NH 8
#define HDm 64
#define SS 128
#define NB 8
#define NL 4
#define QKVW 1536

__device__ __forceinline__ float bf2f(u16 v){ union{uint32_t u; float f;} c; c.u=((uint32_t)v)<<16; return c.f; }
__device__ __forceinline__ u16 f2bf(float f){ union{float f; uint32_t u;} c; c.f=f; uint32_t u=c.u; return (u16)((u + 0x7FFFu + ((u>>16)&1u))>>16); }

__device__ __forceinline__ f32x4 mfma16(bf16x8 a, bf16x8 b, f32x4 c){
  return __builtin_amdgcn_mfma_f32_16x16x32_bf16(a,b,c,0,0,0);
}

__device__ __forceinline__ void gload16(const u16* g, u16* l){
  auto gp = reinterpret_cast<const __attribute__((address_space(1))) uint32_t*>(reinterpret_cast<uintptr_t>(g));
  auto lp = reinterpret_cast<__attribute__((address_space(3))) uint32_t*>(reinterpret_cast<uintptr_t>(l));
  __builtin_amdgcn_global_load_lds(gp, lp, 16, 0, 0);
}

#define ABAR() asm volatile("s_barrier" ::: "memory")
#define SB0()  __builtin_amdgcn_sched_barrier(0)

// map idx -> (local run r, unit u); units-per-run = ((cb+r)/16 + 1) * U
__device__ __forceinline__ void run_map(int bid, int cb, int U, int& r, int& u){
  int rr = 0;
  for (;;){
    int g = (cb + rr) >> 4;
    int gend = ((g + 1) << 4) - cb;
    int upr = (g + 1) * U;
    int span = (gend - rr) * upr;
    if (bid < span){ r = rr + bid / upr; u = bid % upr; return; }
    bid -= span; rr = gend;
  }
}

// ===== fused preamble: 5 weight transposes + bias fuse + hinit + counter zero =====
__global__ __launch_bounds__(256) void prep(const float* __restrict__ Wq, const float* __restrict__ Wk,
                                            const float* __restrict__ Wv, const float* __restrict__ Wo,
                                            const float* __restrict__ Wf,
                                            const float* __restrict__ bq, const float* __restrict__ bk,
                                            const float* __restrict__ bv, const float* __restrict__ x,
                                            u16* __restrict__ WqkvT, u16* __restrict__ WoT,
                                            u16* __restrict__ WfT, float* __restrict__ bqkv,
                                            u16* __restrict__ h0, int* __restrict__ cnt1,
                                            int* __restrict__ cnt2){
  int bid = blockIdx.x;
  int t = threadIdx.x;
  if (bid < 5120){
    __shared__ float tl[32][33];
    int grp = bid >> 10;
    int within = bid & 1023;
    int l = within >> 8, tile = within & 255;
    const float* W; u16* dst; int dstL, dstOff;
    switch(grp){
      case 0: W=Wq; dst=WqkvT; dstL=QKVW*EE; dstOff=0;    break;
      case 1: W=Wk; dst=WqkvT; dstL=QKVW*EE; dstOff=512;  break;
      case 2: W=Wv; dst=WqkvT; dstL=QKVW*EE; dstOff=1024; break;
      case 3: W=Wo; dst=WoT;   dstL=EE*EE;   dstOff=0;    break;
      default:W=Wf; dst=WfT;   dstL=EE*EE;   dstOff=0;    break;
    }
    int ot = tile & 15, it = tile >> 4;
    int c = t & 31, r = t >> 5;
    #pragma unroll
    for (int k=0;k<4;k++){
      int ri = it*32 + r + k*8;
      tl[c][r + k*8] = W[(size_t)l*262144 + (size_t)ri*512 + ot*32 + c];
    }
    __syncthreads();
    #pragma unroll
    for (int k=0;k<4;k++){
      int ro = ot*32 + r + k*8;
      dst[(size_t)l*dstL + (size_t)(dstOff + ro)*512 + it*32 + c] = f2bf(tl[r + k*8][c]);
    }
  } else if (bid < 5144){
    int i = (bid - 5120)*256 + t;     // L*1536 = 6144
    int l = i / QKVW, n = i % QKVW;
    const float* b = (n < 512) ? bq : ((n < 1024) ? bk : bv);
    bqkv[i] = b[l*EE + (n & 511)];
  } else if (bid < 5400){
    int i = ((bid - 5144)*256 + t)*8;
    int e = i & 511;
    int pb = i >> 9;
    int b = pb & 7, pp = pb >> 3;
    const float* xp = x + (((size_t)b*SS + pp)<<9) + e;
    union{ bf16x8 v; u16 u[8]; } rv;
    #pragma unroll
    for (int j=0;j<8;j++) rv.u[j] = f2bf(xp[j]);
    *(bf16x8*)(h0 + i) = rv.v;
  } else {
    // zero tile-completion counters (re-zeroed on every graph replay)
    #pragma unroll
    for (int j=0;j<4;j++){
      cnt1[t*4 + j] = 0;
      cnt2[t*4 + j] = 0;
    }
  }
}

// ===== R9-proven GEMM core + fused tile-LN tail (proper occupancy: LDS = 65536 exactly) =====
// 128x128 tile, BK=64, 4 waves, 2-slot dbuf, counted vmcnt(8), T2 XOR swizzle,
// XCD-aware bijective remap (gridDim.x % 8 == 0). A tile's 4 y-blocks land on one XCD.
// MODE 0: +bias, split planes by n0>>9 (QKV). MODE 1: +bias+res -> tmp, last block LN -> lnout.
// MODE 2: relu(+bias)+res -> tmp, last block LN -> lnout (+f32 out rows p==m_run when last!=0).
template<int MODE>
__global__ __launch_bounds__(256) void gemm_bt(const u16* __restrict__ A, const u16* __restrict__ Bt,
                                               const float* __restrict__ bias, const u16* __restrict__ res,
                                               u16* __restrict__ o0, u16* __restrict__ o1, u16* __restrict__ o2,
                                               int cb, size_t res_mask,
                                               const float* __restrict__ lng, const float* __restrict__ lnb,
                                               u16* __restrict__ lnout, int* cnt,
                                               float* __restrict__ fout, int last){
  __shared__ u16 As[2][128*64];
  __shared__ u16 Bs[2][128*64];
  int t = threadIdx.x;
  int T = gridDim.x, NY = gridDim.y;
  int tile_idx, yb;
  if ((T & 7) == 0){
    int hw = blockIdx.y * T + blockIdx.x;
    int xcd = hw & 7, u = hw >> 3;
    yb = u % NY;
    tile_idx = (u / NY) * 8 + xcd;
  } else { tile_idx = blockIdx.x; yb = blockIdx.y; }
  size_t m0;
  int rrun = 0, tile16 = 0;
  if (cb < 0){
    m0 = (size_t)tile_idx * 128;
  } else {
    run_map(tile_idx, cb, 1, rrun, tile16);
    m0 = (size_t)rrun*1024 + (size_t)tile16*128;
  }
  int n0 = yb*128;
  int wid=t>>6, lane=t&63;
  int wm=wid>>1, wn=wid&1, lr=lane&15, lq=lane>>4;
  f32x4 acc[4][4] = {};
  int srow = t>>3;
  int cg2 = (t&7) ^ (srow&7);
  const u16* gA = A + (m0+(size_t)srow)*EE + cg2*8;
  const u16* gB = Bt + ((size_t)(n0+srow))*EE + cg2*8;

  auto stage = [&](int kt, int slot){
    int k0 = kt*64;
    u16* lA = As[slot] + t*8;
    u16* lB = Bs[slot] + t*8;
    #pragma unroll
    for (int j=0;j<4;j++){
      gload16(gA + (size_t)j*32*EE + k0, lA + j*2048);
      gload16(gB + (size_t)j*32*EE + k0, lB + j*2048);
    }
  };

  stage(0,0); stage(1,1);

  #pragma unroll
  for (int kt=0; kt<8; kt++){
    int slot = kt & 1;
    if (kt < 7) asm volatile("s_waitcnt vmcnt(8)" ::: "memory");
    else        asm volatile("s_waitcnt vmcnt(0)" ::: "memory");
    ABAR();
    bf16x8 a[4][2], b[4][2];
    #pragma unroll
    for (int mi=0;mi<4;mi++){
      int row = wm*64 + mi*16 + lr;
      #pragma unroll
      for (int kk=0;kk<2;kk++){
        int c = (kk*4 + lq) ^ (row&7);
        a[mi][kk] = *(const bf16x8*)(As[slot] + row*64 + c*8);
      }
    }
    #pragma unroll
    for (int ni=0;ni<4;ni++){
      int row = wn*64 + ni*16 + lr;
      #pragma unroll
      for (int kk=0;kk<2;kk++){
        int c = (kk*4 + lq) ^ (row&7);
        b[ni][kk] = *(const bf16x8*)(Bs[slot] + row*64 + c*8);
      }
    }
    asm volatile("s_waitcnt lgkmcnt(0)" ::: "memory");
    SB0();
    ABAR();
    if (kt < 6) stage(kt+2, slot);
    #pragma unroll
    for (int mi=0;mi<4;mi++)
      #pragma unroll
      for (int ni=0;ni<4;ni++){
        acc[mi][ni] = mfma16(a[mi][0], b[ni][0], acc[mi][ni]);
        acc[mi][ni] = mfma16(a[mi][1], b[ni][1], acc[mi][ni]);
      }
  }

  int g4 = lane>>4;
  u16* outp; int nb;
  if (MODE==0){ int sel = n0 >> 9; outp = sel==0 ? o0 : (sel==1 ? o1 : o2); nb = n0 & 511; }
  else        { outp = o0; nb = n0; }
  #pragma unroll
  for (int ni=0;ni<4;ni++){
    int coln = wn*64 + ni*16 + lr;
    float bv = bias[n0 + coln];
    int col = nb + coln;
    #pragma unroll
    for (int mi=0;mi<4;mi++){
      #pragma unroll
      for (int j=0;j<4;j++){
        size_t row = m0 + (size_t)(wm*64 + mi*16 + g4*4 + j);
        float v = acc[mi][ni][j] + bv;
        if (MODE==2) v = fmaxf(v, 0.f);
        if (MODE>=1) v += bf2f(res[(row & res_mask)*EE + col]);
        outp[row*EE + col] = f2bf(v);
      }
    }
  }

  if (MODE==1 || MODE==2){
    __threadfence();                      // release this block's tmp stripe (device scope)
    __syncthreads();                      // all threads' stores fenced; LDS now dead -> reuse As
    int* flagp = (int*)As;
    if (t == 0) flagp[0] = (atomicAdd(&cnt[tile_idx], 1) == 3) ? 1 : 0;
    __syncthreads();
    if (flagp[0]){
      __threadfence();                    // acquire: see the other 3 stripes
      int w = t >> 6;
      int m_run = cb + rrun;
      float gv[8], bv2[8];
      #pragma unroll
      for (int j=0;j<8;j++){ gv[j] = lng[lane*8+j]; bv2[j] = lnb[lane*8+j]; }
      for (int it2=0; it2<32; it2++){
        size_t row = m0 + (size_t)it2*4 + w;
        const u16* pp = o0 + row*EE + lane*8;
        union{ bf16x8 v; u16 u[8]; } d; d.v = *(const bf16x8*)pp;
        float f[8]; float s=0.f;
        #pragma unroll
        for (int j=0;j<8;j++){ f[j]=bf2f(d.u[j]); s+=f[j]; }
        #pragma unroll
        for (int o=1;o<64;o<<=1) s += __shfl_xor(s,o);
        float mu = s*(1.f/512.f);
        float s2=0.f;
        #pragma unroll
        for (int j=0;j<8;j++){ float tt=f[j]-mu; s2+=tt*tt; }
        #pragma unroll
        for (int o=1;o<64;o<<=1) s2 += __shfl_xor(s2,o);
        float rstd = rsqrtf(s2*(1.f/512.f)+1e-5f);
        union{ bf16x8 v; u16 u[8]; } rr;
        #pragma unroll
        for (int j=0;j<8;j++) rr.u[j] = f2bf((f[j]-mu)*rstd*gv[j] + bv2[j]);
        *(bf16x8*)(lnout + row*EE + lane*8) = rr.v;
        if (MODE==2 && last){
          int local = tile16*128 + it2*4 + w;
          int pidx = local >> 3, b3 = local & 7;
          if (pidx == m_run){
            #pragma unroll
            for (int j=0;j<8;j++) fout[((size_t)b3*SS + pidx)*EE + lane*8 + j] = bf2f(rr.u[j]);
          }
        }
      }
      if (t == 0) cnt[tile_idx] = 0;      // restore for next dispatch / replay
    }
  }
}

// one block per (run, batch, head); 512-wide planes; O written into q plane
__global__ __launch_bounds__(256) void attn(const u16* __restrict__ Q, const u16* __restrict__ K,
                                            const u16* __restrict__ V, u16* __restrict__ Oq,
                                            int cb, int shared_qkv){
  __shared__ u16 Ks[128*72];
  __shared__ u16 Vt[64*136];
  __shared__ u16 Ps[4][16*136];
  int t = threadIdx.x;
  int idx = blockIdx.x;
  int hh = idx & 7, b = (idx>>3)&7, r = idx>>6;
  int m_run = cb + r;
  const size_t RS = (size_t)SS*NB*EE;
  size_t rbase = shared_qkv ? 0 : (size_t)r*RS;
  size_t hb = (size_t)b*EE + hh*HDm;
  size_t obase = (size_t)r*RS + hb;
  int nkc = m_run/32 + 1;
  int nkt = nkc*2;
  int nqt = m_run/16 + 1;
  int nkr = nkt*16;
  for (int i=t; i<nkr*8; i+=256){
    int row=i>>3, c=(i&7)*8;
    *(uint4*)(Ks + row*72 + c) = *(const uint4*)(K + rbase + (size_t)row*NB*EE + hb + c);
  }
  for (int i=t; i<nkr*8; i+=256){
    int row=i>>3, c=(i&7)*8;
    uint4 raw = *(const uint4*)(V + rbase + (size_t)row*NB*EE + hb + c);
    const u16* pv = (const u16*)&raw;
    #pragma unroll
    for (int j=0;j<8;j++) Vt[(c+j)*136 + row] = pv[j];
  }
  __syncthreads();
  int wid=t>>6, lane=t&63, lr=lane&15, g=lane>>4, lk=(lane>>4)*8;
  u16* Pw = Ps[wid];
  for (int iq=0; iq<2; iq++){
    int qt = wid*2 + iq;
    if (qt >= nqt) continue;
    const u16* qrow = Q + rbase + (size_t)(qt*16+lr)*NB*EE + hb;
    bf16x8 qa0 = *(const bf16x8*)(qrow + lk);
    bf16x8 qa1 = *(const bf16x8*)(qrow + 32 + lk);
    f32x4 sc[8];
    #pragma unroll
    for (int kt=0;kt<8;kt++){
      if (kt < nkt){
        f32x4 c = {};
        bf16x8 kb0 = *(const bf16x8*)(Ks + (kt*16+lr)*72 + lk);
        bf16x8 kb1 = *(const bf16x8*)(Ks + (kt*16+lr)*72 + 32 + lk);
        c = mfma16(qa0, kb0, c);
        c = mfma16(qa1, kb1, c);
        int key = kt*16 + lr;
        #pragma unroll
        for (int i2=0;i2<4;i2++)
          sc[kt][i2] = (key <= m_run) ? c[i2]*0.125f : -1e9f;
      }
    }
    #pragma unroll
    for (int i2=0;i2<4;i2++){
      float v = -3.0e38f;
      #pragma unroll
      for (int kt=0;kt<8;kt++) if (kt<nkt) v = fmaxf(v, sc[kt][i2]);
      v = fmaxf(v, __shfl_xor(v,1));
      v = fmaxf(v, __shfl_xor(v,2));
      v = fmaxf(v, __shfl_xor(v,4));
      v = fmaxf(v, __shfl_xor(v,8));
      float s = 0.f;
      #pragma unroll
      for (int kt=0;kt<8;kt++) if (kt<nkt){ float e2=__expf(sc[kt][i2]-v); sc[kt][i2]=e2; s+=e2; }
      s += __shfl_xor(s,1); s += __shfl_xor(s,2); s += __shfl_xor(s,4); s += __shfl_xor(s,8);
      float inv = 1.f/s;
      #pragma unroll
      for (int kt=0;kt<8;kt++) if (kt<nkt) sc[kt][i2] *= inv;
    }
    #pragma unroll
    for (int kt=0;kt<8;kt++) if (kt<nkt){
      #pragma unroll
      for (int i2=0;i2<4;i2++)
        Pw[(g*4+i2)*136 + kt*16 + lr] = f2bf(sc[kt][i2]);
    }
    f32x4 oa[4] = {};
    #pragma unroll
    for (int kc=0;kc<4;kc++) if (kc<nkc){
      bf16x8 pa = *(const bf16x8*)(Pw + lr*136 + kc*32 + lk);
      #pragma unroll
      for (int dt=0;dt<4;dt++){
        bf16x8 vb = *(const bf16x8*)(Vt + (dt*16+lr)*136 + kc*32 + lk);
        oa[dt] = mfma16(pa, vb, oa[dt]);
      }
    }
    #pragma unroll
    for (int dt=0;dt<4;dt++){
      #pragma unroll
      for (int j=0;j<4;j++){
        size_t prow = (size_t)(qt*16 + g*4 + j);
        Oq[obase + prow*NB*EE + dt*16 + lr] = f2bf(oa[dt][j]);
      }
    }
  }
}

extern "C" void kernel_launch(void* const* d_in, const int* in_sizes, int n_in,
                              void* d_out, int out_size, void* d_ws, size_t ws_size,
                              hipStream_t stream){
  const float* x   = (const float*)d_in[0];
  const float* Wq  = (const float*)d_in[1];
  const float* bq  = (const float*)d_in[2];
  const float* Wk  = (const float*)d_in[3];
  const float* bk  = (const float*)d_in[4];
  const float* Wv  = (const float*)d_in[5];
  const float* bv  = (const float*)d_in[6];
  const float* Wo  = (const float*)d_in[7];
  const float* bo  = (const float*)d_in[8];
  const float* Wf  = (const float*)d_in[9];
  const float* bfb = (const float*)d_in[10];
  const float* g1  = (const float*)d_in[11];
  const float* b1  = (const float*)d_in[12];
  const float* g2  = (const float*)d_in[13];
  const float* b2  = (const float*)d_in[14];
  float* out = (float*)d_out;

  uint8_t* p = (uint8_t*)d_ws;
  u16* WqkvT = (u16*)p; p += (size_t)NL*QKVW*EE*2;
  u16* WoT   = (u16*)p; p += (size_t)NL*EE*EE*2;
  u16* WfT   = (u16*)p; p += (size_t)NL*EE*EE*2;
  float* bqkv= (float*)p; p += (size_t)NL*QKVW*4;
  u16* h0    = (u16*)p; p += (size_t)SS*NB*EE*2;
  u16* q0    = (u16*)p; p += (size_t)SS*NB*EE*2;
  u16* k0    = (u16*)p; p += (size_t)SS*NB*EE*2;
  u16* v0    = (u16*)p; p += (size_t)SS*NB*EE*2;
  int* cnt1  = (int*)p; p += 1024*4;
  int* cnt2  = (int*)p; p += 1024*4;
  size_t used = (size_t)(p - (uint8_t*)d_ws);

  int RC = 128;
  const size_t PER_RUN = (size_t)SS*NB*EE*2*5;
  while (RC > 1 && used + (size_t)RC*PER_RUN > ws_size) RC >>= 1;

  const size_t BUF = (size_t)RC*SS*NB*EE*2;
  u16* h   = (u16*)p; p += BUF;
  u16* q   = (u16*)p; p += BUF;
  u16* k   = (u16*)p; p += BUF;
  u16* v   = (u16*)p; p += BUF;
  u16* tmp = (u16*)p; p += BUF;

  const size_t NOMASK = ~(size_t)0;
  const size_t QL = (size_t)QKVW*EE;
  const size_t OL = (size_t)EE*EE;

  prep<<<5401,256,0,stream>>>(Wq, Wk, Wv, Wo, Wf, bq, bk, bv, x, WqkvT, WoT, WfT, bqkv, h0, cnt1, cnt2);
  // layer-0 QKV once for all runs (plain tiles, 1024 rows)
  gemm_bt<0><<<dim3(8,12),256,0,stream>>>(h0, WqkvT, bqkv, nullptr, q0, k0, v0, -1, 0,
                                          nullptr, nullptr, nullptr, nullptr, nullptr, 0);

  for (int cb=0; cb<SS; cb+=RC){
    int t128 = 0;
    for (int r2=0;r2<RC;r2++) t128 += (cb+r2)/16 + 1;

    // layer 0
    attn<<<dim3(RC*64),256,0,stream>>>(q0, k0, v0, q, cb, 1);
    gemm_bt<1><<<dim3(t128,4),256,0,stream>>>(q, WoT, bo, h0, tmp, nullptr, nullptr, cb, (size_t)1023,
                                              g1, b1, h, cnt1, nullptr, 0);
    gemm_bt<2><<<dim3(t128,4),256,0,stream>>>(h, WfT, bfb, h, tmp, nullptr, nullptr, cb, NOMASK,
                                              g2, b2, h, cnt2, out, 0);

    for (int l=1;l<NL;l++){
      gemm_bt<0><<<dim3(t128,12),256,0,stream>>>(h, WqkvT+(size_t)l*QL, bqkv+l*QKVW, nullptr, q, k, v,
                                                 cb, 0, nullptr, nullptr, nullptr, nullptr, nullptr, 0);
      attn<<<dim3(RC*64),256,0,stream>>>(q, k, v, q, cb, 0);
      gemm_bt<1><<<dim3(t128,4),256,0,stream>>>(q, WoT+(size_t)l*OL, bo+l*EE, h, tmp, nullptr, nullptr,
                                                cb, NOMASK, g1+l*EE, b1+l*EE, h, cnt1, nullptr, 0);
      gemm_bt<2><<<dim3(t128,4),256,0,stream>>>(h, WfT+(size_t)l*OL, bfb+l*EE, h, tmp, nullptr, nullptr,
                                                cb, NOMASK, g2+l*EE, b2+l*EE, h, cnt2, out,
                                                (l==NL-1) ? 1 : 0);
    }
  }
}

// Round 13
// 1832.132 us; speedup vs baseline: 3.0610x; 3.0610x over previous
//
#include <hip/hip_runtime.h>
#include <stdint.h>

typedef unsigned short u16;
typedef __attribute__((ext_vector_type(8))) short bf16x8;
typedef __attribute__((ext_vector_type(4))) float f32x4;

#define EE 512
#define NH 8
#define HDm 64
#define SS 128
#define NB 8
#define NL 4
#define QKVW 1536

__device__ __forceinline__ float bf2f(u16 v){ union{uint32_t u; float f;} c; c.u=((uint32_t)v)<<16; return c.f; }
__device__ __forceinline__ u16 f2bf(float f){ union{float f; uint32_t u;} c; c.f=f; uint32_t u=c.u; return (u16)((u + 0x7FFFu + ((u>>16)&1u))>>16); }

__device__ __forceinline__ f32x4 mfma16(bf16x8 a, bf16x8 b, f32x4 c){
  return __builtin_amdgcn_mfma_f32_16x16x32_bf16(a,b,c,0,0,0);
}

__device__ __forceinline__ void gload16(const u16* g, u16* l){
  auto gp = reinterpret_cast<const __attribute__((address_space(1))) uint32_t*>(reinterpret_cast<uintptr_t>(g));
  auto lp = reinterpret_cast<__attribute__((address_space(3))) uint32_t*>(reinterpret_cast<uintptr_t>(l));
  __builtin_amdgcn_global_load_lds(gp, lp, 16, 0, 0);
}

#define ABAR() asm volatile("s_barrier" ::: "memory")
#define SB0()  __builtin_amdgcn_sched_barrier(0)

// map idx -> (local run r, unit u); units-per-run = ((cb+r)/16 + 1) * U
__device__ __forceinline__ void run_map(int bid, int cb, int U, int& r, int& u){
  int rr = 0;
  for (;;){
    int g = (cb + rr) >> 4;
    int gend = ((g + 1) << 4) - cb;
    int upr = (g + 1) * U;
    int span = (gend - rr) * upr;
    if (bid < span){ r = rr + bid / upr; u = bid % upr; return; }
    bid -= span; rr = gend;
  }
}

// ===== fused preamble: 5 weight transposes + bias fuse + hinit =====
__global__ __launch_bounds__(256) void prep(const float* __restrict__ Wq, const float* __restrict__ Wk,
                                            const float* __restrict__ Wv, const float* __restrict__ Wo,
                                            const float* __restrict__ Wf,
                                            const float* __restrict__ bq, const float* __restrict__ bk,
                                            const float* __restrict__ bv, const float* __restrict__ x,
                                            u16* __restrict__ WqkvT, u16* __restrict__ WoT,
                                            u16* __restrict__ WfT, float* __restrict__ bqkv,
                                            u16* __restrict__ h0){
  int bid = blockIdx.x;
  int t = threadIdx.x;
  if (bid < 5120){
    __shared__ float tl[32][33];
    int grp = bid >> 10;
    int within = bid & 1023;
    int l = within >> 8, tile = within & 255;
    const float* W; u16* dst; int dstL, dstOff;
    switch(grp){
      case 0: W=Wq; dst=WqkvT; dstL=QKVW*EE; dstOff=0;    break;
      case 1: W=Wk; dst=WqkvT; dstL=QKVW*EE; dstOff=512;  break;
      case 2: W=Wv; dst=WqkvT; dstL=QKVW*EE; dstOff=1024; break;
      case 3: W=Wo; dst=WoT;   dstL=EE*EE;   dstOff=0;    break;
      default:W=Wf; dst=WfT;   dstL=EE*EE;   dstOff=0;    break;
    }
    int ot = tile & 15, it = tile >> 4;
    int c = t & 31, r = t >> 5;
    #pragma unroll
    for (int k=0;k<4;k++){
      int ri = it*32 + r + k*8;
      tl[c][r + k*8] = W[(size_t)l*262144 + (size_t)ri*512 + ot*32 + c];
    }
    __syncthreads();
    #pragma unroll
    for (int k=0;k<4;k++){
      int ro = ot*32 + r + k*8;
      dst[(size_t)l*dstL + (size_t)(dstOff + ro)*512 + it*32 + c] = f2bf(tl[r + k*8][c]);
    }
  } else if (bid < 5144){
    int i = (bid - 5120)*256 + t;     // L*1536 = 6144
    int l = i / QKVW, n = i % QKVW;
    const float* b = (n < 512) ? bq : ((n < 1024) ? bk : bv);
    bqkv[i] = b[l*EE + (n & 511)];
  } else {
    int i = ((bid - 5144)*256 + t)*8;
    int e = i & 511;
    int pb = i >> 9;
    int b = pb & 7, pp = pb >> 3;
    const float* xp = x + (((size_t)b*SS + pp)<<9) + e;
    union{ bf16x8 v; u16 u[8]; } rv;
    #pragma unroll
    for (int j=0;j<8;j++) rv.u[j] = f2bf(xp[j]);
    *(bf16x8*)(h0 + i) = rv.v;
  }
}

// ===== R9-proven GEMM: 128x128, BK=64, 4 waves, 2-slot dbuf, vmcnt(8), T2 swizzle, XCD remap =====
// MODE 0: +bias, split planes by n0>>9 (QKV); 1: +bias+res; 2: relu(+bias)+res
template<int MODE>
__global__ __launch_bounds__(256) void gemm_bt(const u16* __restrict__ A, const u16* __restrict__ Bt,
                                               const float* __restrict__ bias, const u16* __restrict__ res,
                                               u16* __restrict__ o0, u16* __restrict__ o1, u16* __restrict__ o2,
                                               int cb, size_t res_mask){
  __shared__ u16 As[2][128*64];
  __shared__ u16 Bs[2][128*64];
  int t = threadIdx.x;
  int T = gridDim.x, NY = gridDim.y;
  int tile_idx, yb;
  if ((T & 7) == 0){
    int hw = blockIdx.y * T + blockIdx.x;
    int xcd = hw & 7, u = hw >> 3;
    yb = u % NY;
    tile_idx = (u / NY) * 8 + xcd;
  } else { tile_idx = blockIdx.x; yb = blockIdx.y; }
  size_t m0;
  if (cb < 0){
    m0 = (size_t)tile_idx * 128;
  } else {
    int r, tile; run_map(tile_idx, cb, 1, r, tile);
    m0 = (size_t)r*1024 + (size_t)tile*128;
  }
  int n0 = yb*128;
  int wid=t>>6, lane=t&63;
  int wm=wid>>1, wn=wid&1, lr=lane&15, lq=lane>>4;
  f32x4 acc[4][4] = {};
  int srow = t>>3;
  int cg2 = (t&7) ^ (srow&7);
  const u16* gA = A + (m0+(size_t)srow)*EE + cg2*8;
  const u16* gB = Bt + ((size_t)(n0+srow))*EE + cg2*8;

  auto stage = [&](int kt, int slot){
    int k0 = kt*64;
    u16* lA = As[slot] + t*8;
    u16* lB = Bs[slot] + t*8;
    #pragma unroll
    for (int j=0;j<4;j++){
      gload16(gA + (size_t)j*32*EE + k0, lA + j*2048);
      gload16(gB + (size_t)j*32*EE + k0, lB + j*2048);
    }
  };

  stage(0,0); stage(1,1);

  #pragma unroll
  for (int kt=0; kt<8; kt++){
    int slot = kt & 1;
    if (kt < 7) asm volatile("s_waitcnt vmcnt(8)" ::: "memory");
    else        asm volatile("s_waitcnt vmcnt(0)" ::: "memory");
    ABAR();
    bf16x8 a[4][2], b[4][2];
    #pragma unroll
    for (int mi=0;mi<4;mi++){
      int row = wm*64 + mi*16 + lr;
      #pragma unroll
      for (int kk=0;kk<2;kk++){
        int c = (kk*4 + lq) ^ (row&7);
        a[mi][kk] = *(const bf16x8*)(As[slot] + row*64 + c*8);
      }
    }
    #pragma unroll
    for (int ni=0;ni<4;ni++){
      int row = wn*64 + ni*16 + lr;
      #pragma unroll
      for (int kk=0;kk<2;kk++){
        int c = (kk*4 + lq) ^ (row&7);
        b[ni][kk] = *(const bf16x8*)(Bs[slot] + row*64 + c*8);
      }
    }
    asm volatile("s_waitcnt lgkmcnt(0)" ::: "memory");
    SB0();
    ABAR();
    if (kt < 6) stage(kt+2, slot);
    #pragma unroll
    for (int mi=0;mi<4;mi++)
      #pragma unroll
      for (int ni=0;ni<4;ni++){
        acc[mi][ni] = mfma16(a[mi][0], b[ni][0], acc[mi][ni]);
        acc[mi][ni] = mfma16(a[mi][1], b[ni][1], acc[mi][ni]);
      }
  }

  int g4 = lane>>4;
  u16* outp;
  int nb;
  if (MODE==0){ int sel = n0 >> 9; outp = sel==0 ? o0 : (sel==1 ? o1 : o2); nb = n0 & 511; }
  else        { outp = o0; nb = n0; }
  #pragma unroll
  for (int ni=0;ni<4;ni++){
    int coln = wn*64 + ni*16 + lr;
    float bv = bias[n0 + coln];
    int col = nb + coln;
    #pragma unroll
    for (int mi=0;mi<4;mi++){
      #pragma unroll
      for (int j=0;j<4;j++){
        size_t row = m0 + (size_t)(wm*64 + mi*16 + g4*4 + j);
        float v = acc[mi][ni][j] + bv;
        if (MODE==2) v = fmaxf(v, 0.f);
        if (MODE>=1) v += bf2f(res[(row & res_mask)*EE + col]);
        outp[row*EE + col] = f2bf(v);
      }
    }
  }
}

// one block per (run, batch, head); 512-wide planes; O written into q plane
__global__ __launch_bounds__(256) void attn(const u16* __restrict__ Q, const u16* __restrict__ K,
                                            const u16* __restrict__ V, u16* __restrict__ Oq,
                                            int cb, int shared_qkv){
  __shared__ u16 Ks[128*72];
  __shared__ u16 Vt[64*136];
  __shared__ u16 Ps[4][16*136];
  int t = threadIdx.x;
  int idx = blockIdx.x;
  int hh = idx & 7, b = (idx>>3)&7, r = idx>>6;
  int m_run = cb + r;
  const size_t RS = (size_t)SS*NB*EE;
  size_t rbase = shared_qkv ? 0 : (size_t)r*RS;
  size_t hb = (size_t)b*EE + hh*HDm;
  size_t obase = (size_t)r*RS + hb;
  int nkc = m_run/32 + 1;
  int nkt = nkc*2;
  int nqt = m_run/16 + 1;
  int nkr = nkt*16;
  for (int i=t; i<nkr*8; i+=256){
    int row=i>>3, c=(i&7)*8;
    *(uint4*)(Ks + row*72 + c) = *(const uint4*)(K + rbase + (size_t)row*NB*EE + hb + c);
  }
  for (int i=t; i<nkr*8; i+=256){
    int row=i>>3, c=(i&7)*8;
    uint4 raw = *(const uint4*)(V + rbase + (size_t)row*NB*EE + hb + c);
    const u16* pv = (const u16*)&raw;
    #pragma unroll
    for (int j=0;j<8;j++) Vt[(c+j)*136 + row] = pv[j];
  }
  __syncthreads();
  int wid=t>>6, lane=t&63, lr=lane&15, g=lane>>4, lk=(lane>>4)*8;
  u16* Pw = Ps[wid];
  for (int iq=0; iq<2; iq++){
    int qt = wid*2 + iq;
    if (qt >= nqt) continue;
    const u16* qrow = Q + rbase + (size_t)(qt*16+lr)*NB*EE + hb;
    bf16x8 qa0 = *(const bf16x8*)(qrow + lk);
    bf16x8 qa1 = *(const bf16x8*)(qrow + 32 + lk);
    f32x4 sc[8];
    #pragma unroll
    for (int kt=0;kt<8;kt++){
      if (kt < nkt){
        f32x4 c = {};
        bf16x8 kb0 = *(const bf16x8*)(Ks + (kt*16+lr)*72 + lk);
        bf16x8 kb1 = *(const bf16x8*)(Ks + (kt*16+lr)*72 + 32 + lk);
        c = mfma16(qa0, kb0, c);
        c = mfma16(qa1, kb1, c);
        int key = kt*16 + lr;
        #pragma unroll
        for (int i2=0;i2<4;i2++)
          sc[kt][i2] = (key <= m_run) ? c[i2]*0.125f : -1e9f;
      }
    }
    #pragma unroll
    for (int i2=0;i2<4;i2++){
      float v = -3.0e38f;
      #pragma unroll
      for (int kt=0;kt<8;kt++) if (kt<nkt) v = fmaxf(v, sc[kt][i2]);
      v = fmaxf(v, __shfl_xor(v,1));
      v = fmaxf(v, __shfl_xor(v,2));
      v = fmaxf(v, __shfl_xor(v,4));
      v = fmaxf(v, __shfl_xor(v,8));
      float s = 0.f;
      #pragma unroll
      for (int kt=0;kt<8;kt++) if (kt<nkt){ float e2=__expf(sc[kt][i2]-v); sc[kt][i2]=e2; s+=e2; }
      s += __shfl_xor(s,1); s += __shfl_xor(s,2); s += __shfl_xor(s,4); s += __shfl_xor(s,8);
      float inv = 1.f/s;
      #pragma unroll
      for (int kt=0;kt<8;kt++) if (kt<nkt) sc[kt][i2] *= inv;
    }
    #pragma unroll
    for (int kt=0;kt<8;kt++) if (kt<nkt){
      #pragma unroll
      for (int i2=0;i2<4;i2++)
        Pw[(g*4+i2)*136 + kt*16 + lr] = f2bf(sc[kt][i2]);
    }
    f32x4 oa[4] = {};
    #pragma unroll
    for (int kc=0;kc<4;kc++) if (kc<nkc){
      bf16x8 pa = *(const bf16x8*)(Pw + lr*136 + kc*32 + lk);
      #pragma unroll
      for (int dt=0;dt<4;dt++){
        bf16x8 vb = *(const bf16x8*)(Vt + (dt*16+lr)*136 + kc*32 + lk);
        oa[dt] = mfma16(pa, vb, oa[dt]);
      }
    }
    #pragma unroll
    for (int dt=0;dt<4;dt++){
      #pragma unroll
      for (int j=0;j<4;j++){
        size_t prow = (size_t)(qt*16 + g*4 + j);
        Oq[obase + prow*NB*EE + dt*16 + lr] = f2bf(oa[dt][j]);
      }
    }
  }
}

// LN over E=512; one wave per row; run-mapped (U=8 -> 16 rows per unit).
// last!=0: also write f32 output rows (p == m_run) to fout.
__global__ __launch_bounds__(256) void lnorm(const u16* __restrict__ in, const float* __restrict__ gg,
                                             const float* __restrict__ bb, u16* __restrict__ outp,
                                             float* __restrict__ fout, int last, int cb){
  int r, u; run_map(blockIdx.x, cb, 8, r, u);
  int lane = threadIdx.x & 63;
  float gv[8], bv2[8];
  #pragma unroll
  for (int j=0;j<8;j++){ gv[j] = gg[lane*8+j]; bv2[j] = bb[lane*8+j]; }
  int m_run = cb + r;
  #pragma unroll
  for (int it=0; it<4; it++){
    int local = u*16 + it*4 + (threadIdx.x>>6);
    size_t row = (size_t)r*1024 + local;
    const u16* p = in + row*EE + lane*8;
    union{ bf16x8 v; u16 u[8]; } d; d.v = *(const bf16x8*)p;
    float f[8]; float s=0.f;
    #pragma unroll
    for (int j=0;j<8;j++){ f[j]=bf2f(d.u[j]); s+=f[j]; }
    #pragma unroll
    for (int o=1;o<64;o<<=1) s += __shfl_xor(s,o);
    float mu = s*(1.f/512.f);
    float s2=0.f;
    #pragma unroll
    for (int j=0;j<8;j++){ float tt=f[j]-mu; s2+=tt*tt; }
    #pragma unroll
    for (int o=1;o<64;o<<=1) s2 += __shfl_xor(s2,o);
    float rstd = rsqrtf(s2*(1.f/512.f)+1e-5f);
    union{ bf16x8 v; u16 u[8]; } rr;
    #pragma unroll
    for (int j=0;j<8;j++) rr.u[j] = f2bf((f[j]-mu)*rstd*gv[j] + bv2[j]);
    *(bf16x8*)(outp + row*EE + lane*8) = rr.v;
    if (last){
      int pidx = local >> 3, b3 = local & 7;
      if (pidx == m_run){
        #pragma unroll
        for (int j=0;j<8;j++) fout[((size_t)b3*SS + pidx)*EE + lane*8 + j] = bf2f(rr.u[j]);
      }
    }
  }
}

extern "C" void kernel_launch(void* const* d_in, const int* in_sizes, int n_in,
                              void* d_out, int out_size, void* d_ws, size_t ws_size,
                              hipStream_t stream){
  const float* x   = (const float*)d_in[0];
  const float* Wq  = (const float*)d_in[1];
  const float* bq  = (const float*)d_in[2];
  const float* Wk  = (const float*)d_in[3];
  const float* bk  = (const float*)d_in[4];
  const float* Wv  = (const float*)d_in[5];
  const float* bv  = (const float*)d_in[6];
  const float* Wo  = (const float*)d_in[7];
  const float* bo  = (const float*)d_in[8];
  const float* Wf  = (const float*)d_in[9];
  const float* bfb = (const float*)d_in[10];
  const float* g1  = (const float*)d_in[11];
  const float* b1  = (const float*)d_in[12];
  const float* g2  = (const float*)d_in[13];
  const float* b2  = (const float*)d_in[14];
  float* out = (float*)d_out;

  uint8_t* p = (uint8_t*)d_ws;
  u16* WqkvT = (u16*)p; p += (size_t)NL*QKVW*EE*2;
  u16* WoT   = (u16*)p; p += (size_t)NL*EE*EE*2;
  u16* WfT   = (u16*)p; p += (size_t)NL*EE*EE*2;
  float* bqkv= (float*)p; p += (size_t)NL*QKVW*4;
  u16* h0    = (u16*)p; p += (size_t)SS*NB*EE*2;
  u16* q0    = (u16*)p; p += (size_t)SS*NB*EE*2;
  u16* k0    = (u16*)p; p += (size_t)SS*NB*EE*2;
  u16* v0    = (u16*)p; p += (size_t)SS*NB*EE*2;
  size_t used = (size_t)(p - (uint8_t*)d_ws);

  int RC = 128;
  const size_t PER_RUN = (size_t)SS*NB*EE*2*5;
  while (RC > 1 && used + (size_t)RC*PER_RUN > ws_size) RC >>= 1;

  const size_t BUF = (size_t)RC*SS*NB*EE*2;
  u16* h   = (u16*)p; p += BUF;
  u16* q   = (u16*)p; p += BUF;
  u16* k   = (u16*)p; p += BUF;
  u16* v   = (u16*)p; p += BUF;
  u16* tmp = (u16*)p; p += BUF;

  const size_t NOMASK = ~(size_t)0;
  const size_t QL = (size_t)QKVW*EE;
  const size_t OL = (size_t)EE*EE;

  prep<<<5400,256,0,stream>>>(Wq, Wk, Wv, Wo, Wf, bq, bk, bv, x, WqkvT, WoT, WfT, bqkv, h0);
  // layer-0 QKV once for all runs (plain tiles, 1024 rows)
  gemm_bt<0><<<dim3(8,12),256,0,stream>>>(h0, WqkvT, bqkv, nullptr, q0, k0, v0, -1, 0);

  for (int cb=0; cb<SS; cb+=RC){
    int t128 = 0;
    for (int r2=0;r2<RC;r2++) t128 += (cb+r2)/16 + 1;

    // layer 0
    attn<<<dim3(RC*64),256,0,stream>>>(q0, k0, v0, q, cb, 1);
    gemm_bt<1><<<dim3(t128,4),256,0,stream>>>(q, WoT, bo, h0, tmp, nullptr, nullptr, cb, (size_t)1023);
    lnorm<<<dim3(t128*8),256,0,stream>>>(tmp, g1, b1, h, nullptr, 0, cb);
    gemm_bt<2><<<dim3(t128,4),256,0,stream>>>(h, WfT, bfb, h, tmp, nullptr, nullptr, cb, NOMASK);
    lnorm<<<dim3(t128*8),256,0,stream>>>(tmp, g2, b2, h, nullptr, 0, cb);

    for (int l=1;l<NL;l++){
      gemm_bt<0><<<dim3(t128,12),256,0,stream>>>(h, WqkvT+(size_t)l*QL, bqkv+l*QKVW, nullptr, q, k, v, cb, 0);
      attn<<<dim3(RC*64),256,0,stream>>>(q, k, v, q, cb, 0);
      gemm_bt<1><<<dim3(t128,4),256,0,stream>>>(q, WoT+(size_t)l*OL, bo+l*EE, h, tmp, nullptr, nullptr, cb, NOMASK);
      lnorm<<<dim3(t128*8),256,0,stream>>>(tmp, g1+l*EE, b1+l*EE, h, nullptr, 0, cb);
      gemm_bt<2><<<dim3(t128,4),256,0,stream>>>(h, WfT+(size_t)l*OL, bfb+l*EE, h, tmp, nullptr, nullptr, cb, NOMASK);
      lnorm<<<dim3(t128*8),256,0,stream>>>(tmp, g2+l*EE, b2+l*EE, h, out, (l==NL-1) ? 1 : 0, cb);
    }
  }
}